// Round 4
// baseline (3273.475 us; speedup 1.0000x reference)
//
#include <hip/hip_runtime.h>
#include <hip/hip_bf16.h>
#include <math.h>

#define NNODES 50000
#define NEDGES 1600000
#define NODEF 92
#define EDGEF 41
#define HID 128
#define NCONV 3
#define NGRAPHS 256
#define ZDIM 297            // 2*HID + EDGEF
#define KSTEPS 10           // wf layout: 10 ksteps of 32 covering k 0..319
#define KS0 4               // edge kernel starts at kstep 4 (k=128)
#define NKS 6               // edge kernel ksteps (k 128..319)
#define ME 32               // edges per block
#define ZLD2 200            // f16 leading dim for edge z (100 words % 32 = 4 -> 2-way free)
#define NLD 136             // f16 leading dim for node staging
#define CLD 132             // f32 leading dim for contribution matrix

typedef _Float16 half8 __attribute__((ext_vector_type(8)));
typedef _Float16 half4 __attribute__((ext_vector_type(4)));
typedef float f32x4 __attribute__((ext_vector_type(4)));

__device__ __forceinline__ float softplus_f(float x) {
    return fmaxf(x, 0.f) + __logf(1.f + __expf(-fabsf(x)));
}
__device__ __forceinline__ float sigmoid_f(float x) {
    return __builtin_amdgcn_rcpf(1.f + __expf(-x));
}

// ---------------- counting sort of edges by dst ----------------
__global__ void hist_kernel(const int* __restrict__ ei, int* __restrict__ cnt) {
    const int e = blockIdx.x * blockDim.x + threadIdx.x;
    if (e < NEDGES) atomicAdd(&cnt[ei[e]], 1);
}

#define SCAN_T 1024
__global__ __launch_bounds__(1024) void scan_kernel(const int* __restrict__ cnt,
                                                    int* __restrict__ cursor) {
    __shared__ int part[SCAN_T];
    const int tid = threadIdx.x;
    const int chunk = (NNODES + SCAN_T - 1) / SCAN_T;
    const int base = tid * chunk;
    int s = 0;
    for (int i = 0; i < chunk; ++i) {
        const int idx = base + i;
        if (idx < NNODES) s += cnt[idx];
    }
    part[tid] = s;
    __syncthreads();
    for (int off = 1; off < SCAN_T; off <<= 1) {
        int v = 0;
        if (tid >= off) v = part[tid - off];
        __syncthreads();
        part[tid] += v;
        __syncthreads();
    }
    int run = part[tid] - s;   // exclusive prefix
    for (int i = 0; i < chunk; ++i) {
        const int idx = base + i;
        if (idx < NNODES) { cursor[idx] = run; run += cnt[idx]; }
    }
}

__global__ void scatter_kernel(const int* __restrict__ ei, int* __restrict__ cursor,
                               int* __restrict__ perm, int* __restrict__ dstS,
                               int* __restrict__ srcS) {
    const int e = blockIdx.x * blockDim.x + threadIdx.x;
    if (e < NEDGES) {
        const int d = ei[e];
        const int p = atomicAdd(&cursor[d], 1);
        perm[p] = e;
        dstS[p] = d;
        srcS[p] = ei[NEDGES + e];
    }
}

// ---------------- weight fragments ----------------
// wf[((l*16 + g)*KSTEPS + ks)*64 + lane]: tile g: branch=g&1 (0=msg,1=gate),
// j=(g>>2)*32+((g>>1)&1)*16+(lane&15), k=ks*32+(lane>>4)*8+jj
__global__ void prep_wfrag(const float* __restrict__ msg_w, const float* __restrict__ gate_w,
                           half8* __restrict__ wf) {
    const int idx = blockIdx.x * blockDim.x + threadIdx.x;
    const int total = NCONV * 16 * KSTEPS * 64;
    if (idx >= total) return;
    const int lane = idx & 63;
    const int rest = idx >> 6;
    const int ks = rest % KSTEPS;
    const int gl = rest / KSTEPS;
    const int g = gl & 15;
    const int l = gl >> 4;
    const int branch = g & 1;
    const int j = (g >> 2) * 32 + ((g >> 1) & 1) * 16 + (lane & 15);
    const int k0 = ks * 32 + (lane >> 4) * 8;
    const float* W = branch ? gate_w : msg_w;
    half8 v;
    #pragma unroll
    for (int jj = 0; jj < 8; ++jj) {
        const int k = k0 + jj;
        const float f = (k < ZDIM) ? W[((size_t)l * ZDIM + k) * HID + j] : 0.f;
        v[jj] = (_Float16)f;
    }
    wf[idx] = v;
}

__global__ void embed_kernel(const float* __restrict__ x, const float* __restrict__ w,
                             const float* __restrict__ b, float* __restrict__ h) {
    __shared__ float xs[NODEF];
    const int n = blockIdx.x;
    const int j = threadIdx.x;
    if (j < NODEF) xs[j] = x[(size_t)n * NODEF + j];
    __syncthreads();
    float acc = b[j];
    #pragma unroll 4
    for (int k = 0; k < NODEF; ++k) acc = fmaf(xs[k], w[k * HID + j], acc);
    h[(size_t)n * HID + j] = acc;
}

// ---------------- per-node precompute: nprec[n][branch*128+j] = x_i@W1 + bias ----------------
__global__ __launch_bounds__(256) void node_pre_kernel(
    const float* __restrict__ h, const half8* __restrict__ wf,
    const float* __restrict__ bm, const float* __restrict__ bg,
    float* __restrict__ nprec) {
    __shared__ __align__(16) _Float16 zn[32][NLD];
    const int t = threadIdx.x;
    const int nb = blockIdx.x * 32;
    #pragma unroll
    for (int i = 0; i < 4; ++i) {
        const int idx = t + 256 * i;
        const int r = idx >> 5;
        const int c4 = idx & 31;
        const int n = (nb + r < NNODES) ? nb + r : NNODES - 1;
        const float4 v = ((const float4*)(h + (size_t)n * HID))[c4];
        *(half4*)&zn[r][c4 * 4] = (half4){(_Float16)v.x, (_Float16)v.y,
                                          (_Float16)v.z, (_Float16)v.w};
    }
    __syncthreads();
    const int wave = t >> 6, lane = t & 63;
    const int arow = lane & 15, koff = (lane >> 4) * 8;
    f32x4 acc[2][4];
    #pragma unroll
    for (int m = 0; m < 2; ++m)
        #pragma unroll
        for (int n = 0; n < 4; ++n) acc[m][n] = (f32x4){0.f, 0.f, 0.f, 0.f};
    const half8* wfw = wf + (size_t)(wave * 4) * KSTEPS * 64 + lane;
    #pragma unroll
    for (int ks = 0; ks < 4; ++ks) {
        const int kb = ks * 32 + koff;
        const half8 a0 = *(const half8*)&zn[arow][kb];
        const half8 a1 = *(const half8*)&zn[16 + arow][kb];
        #pragma unroll
        for (int nt = 0; nt < 4; ++nt) {
            const half8 b = wfw[(size_t)(nt * KSTEPS + ks) * 64];
            acc[0][nt] = __builtin_amdgcn_mfma_f32_16x16x32_f16(a0, b, acc[0][nt], 0, 0, 0);
            acc[1][nt] = __builtin_amdgcn_mfma_f32_16x16x32_f16(a1, b, acc[1][nt], 0, 0, 0);
        }
    }
    const int l15 = lane & 15;
    #pragma unroll
    for (int nt = 0; nt < 4; ++nt) {
        const int branch = nt & 1;
        const int j = wave * 32 + ((nt >> 1) & 1) * 16 + l15;
        const float bias = branch ? bg[j] : bm[j];
        const int col = branch * 128 + j;
        #pragma unroll
        for (int m = 0; m < 2; ++m)
            #pragma unroll
            for (int r = 0; r < 4; ++r) {
                const int n = nb + m * 16 + ((lane >> 4) & 3) * 4 + r;
                if (n < NNODES) nprec[(size_t)n * 256 + col] = acc[m][nt][r] + bias;
            }
    }
}

// ---------------- edge kernel: x_j|ea GEMM + nprec add + segmented reduce ----------------
__global__ __launch_bounds__(256) void edge_mfma_kernel(
    const float* __restrict__ h, const int* __restrict__ dstS, const int* __restrict__ srcS,
    const int* __restrict__ perm, const float* __restrict__ ea, const half8* __restrict__ wf,
    const float* __restrict__ nprec, float* __restrict__ aggr) {
    __shared__ __align__(16) unsigned char smem_u[32 * CLD * 4];   // 16896 B union
    __shared__ const float4* ssrcp[ME];
    __shared__ const float* seap[ME];
    __shared__ const float* snp[ME];
    __shared__ int sdstv[ME];

    _Float16 (*zs)[ZLD2] = (_Float16(*)[ZLD2])smem_u;   // 32*200*2 = 12800 B
    float* cont = (float*)smem_u;                        // 32*132*4 = 16896 B

    const int t = threadIdx.x;
    const int eb = blockIdx.x * ME;
    if (t < ME) {
        const int d = dstS[eb + t];
        sdstv[t] = d;
        snp[t] = nprec + (size_t)d * 256;
    } else if (t < 2 * ME) {
        ssrcp[t - ME] = (const float4*)(h + (size_t)srcS[eb + t - ME] * HID);
    } else if (t < 3 * ME) {
        seap[t - 2 * ME] = ea + (size_t)perm[eb + t - 2 * ME] * EDGEF;
    }
    __syncthreads();

    // stage x_j (local k 0..127)
    #pragma unroll
    for (int i = 0; i < 4; ++i) {
        const int idx = t + 256 * i;
        const int r = idx >> 5;
        const int c4 = idx & 31;
        const float4 v = ssrcp[r][c4];
        *(half4*)&zs[r][c4 * 4] = (half4){(_Float16)v.x, (_Float16)v.y,
                                          (_Float16)v.z, (_Float16)v.w};
    }
    // stage ea (local k 128..191, zero pad past EDGEF)
    #pragma unroll
    for (int i = 0; i < 8; ++i) {
        const int idx = t + 256 * i;
        const int r = idx >> 6;
        const int kk = idx & 63;
        const float f = (kk < EDGEF) ? seap[r][kk] : 0.f;
        zs[r][128 + kk] = (_Float16)f;
    }
    __syncthreads();

    const int wave = t >> 6, lane = t & 63;
    const int arow = lane & 15, koff = (lane >> 4) * 8;
    f32x4 acc[2][4];
    #pragma unroll
    for (int m = 0; m < 2; ++m)
        #pragma unroll
        for (int n = 0; n < 4; ++n) acc[m][n] = (f32x4){0.f, 0.f, 0.f, 0.f};

    const half8* wfw = wf + (size_t)(wave * 4) * KSTEPS * 64 + lane;
    #pragma unroll
    for (int ks = 0; ks < NKS; ++ks) {
        const int kb = ks * 32 + koff;
        const half8 a0 = *(const half8*)&zs[arow][kb];
        const half8 a1 = *(const half8*)&zs[16 + arow][kb];
        #pragma unroll
        for (int nt = 0; nt < 4; ++nt) {
            const half8 b = wfw[(size_t)(nt * KSTEPS + KS0 + ks) * 64];
            acc[0][nt] = __builtin_amdgcn_mfma_f32_16x16x32_f16(a0, b, acc[0][nt], 0, 0, 0);
            acc[1][nt] = __builtin_amdgcn_mfma_f32_16x16x32_f16(a1, b, acc[1][nt], 0, 0, 0);
        }
    }
    __syncthreads();   // all zs reads done before overwriting as cont

    // epilogue: add nprec (x_i@W + bias), activations, write contributions
    const int j0 = wave * 32 + (lane & 15);
    #pragma unroll
    for (int m = 0; m < 2; ++m) {
        #pragma unroll
        for (int r = 0; r < 4; ++r) {
            const int row = m * 16 + (lane >> 4) * 4 + r;
            const float* np = snp[row];
            const float g0 = sigmoid_f(acc[m][0][r] + np[j0]);
            const float s0 = softplus_f(acc[m][1][r] + np[128 + j0]);
            cont[row * CLD + j0] = g0 * s0;
            const float g1 = sigmoid_f(acc[m][2][r] + np[j0 + 16]);
            const float s1 = softplus_f(acc[m][3][r] + np[128 + j0 + 16]);
            cont[row * CLD + j0 + 16] = g1 * s1;
        }
    }
    __syncthreads();

    // segmented reduce over sorted dst (wave-uniform branches)
    const int c = t & 127;
    const int r0 = (t >> 7) * 16;
    float s = cont[r0 * CLD + c];
    int prev = sdstv[r0];
    #pragma unroll
    for (int r = r0 + 1; r < r0 + 16; ++r) {
        const int d = sdstv[r];
        if (d != prev) {
            atomicAdd(&aggr[(size_t)prev * HID + c], s);
            s = 0.f;
            prev = d;
        }
        s += cont[r * CLD + c];
    }
    atomicAdd(&aggr[(size_t)prev * HID + c], s);
}

__global__ void update_kernel(float* __restrict__ h, const float* __restrict__ aggr) {
    const size_t idx = (size_t)blockIdx.x * blockDim.x + threadIdx.x;
    float4 hv = ((const float4*)h)[idx];
    const float4 av = ((const float4*)aggr)[idx];
    hv.x = softplus_f(hv.x + av.x);
    hv.y = softplus_f(hv.y + av.y);
    hv.z = softplus_f(hv.z + av.z);
    hv.w = softplus_f(hv.w + av.w);
    ((float4*)h)[idx] = hv;
}

__global__ void readout_kernel(const float* __restrict__ h, const int* __restrict__ batch,
                               const float* __restrict__ ro1w, const float* __restrict__ ro1b,
                               const float* __restrict__ ro2w, const float* __restrict__ ro2b,
                               float* __restrict__ out) {
    __shared__ float pooled[HID];
    __shared__ float red[HID];
    __shared__ int range[2];
    const int g = blockIdx.x, j = threadIdx.x;
    if (j == 0) {
        int lo = 0, hi = NNODES;
        while (lo < hi) { int mid = (lo + hi) >> 1; if (batch[mid] < g) lo = mid + 1; else hi = mid; }
        range[0] = lo;
        hi = NNODES;
        while (lo < hi) { int mid = (lo + hi) >> 1; if (batch[mid] < g + 1) lo = mid + 1; else hi = mid; }
        range[1] = lo;
    }
    __syncthreads();
    const int start = range[0], end = range[1];
    float s = 0.f;
    for (int n = start; n < end; ++n) s += h[(size_t)n * HID + j];
    const float cnt = (float)(end - start);
    pooled[j] = s / fmaxf(cnt, 1.f);
    __syncthreads();
    float acc = ro1b[j];
    #pragma unroll 4
    for (int k = 0; k < HID; ++k) acc = fmaf(pooled[k], ro1w[k * HID + j], acc);
    red[j] = softplus_f(acc) * ro2w[j];
    __syncthreads();
    for (int sdt = 64; sdt > 0; sdt >>= 1) {
        if (j < sdt) red[j] += red[j + sdt];
        __syncthreads();
    }
    if (j == 0) out[g] = red[0] + ro2b[0];
}

extern "C" void kernel_launch(void* const* d_in, const int* in_sizes, int n_in,
                              void* d_out, int out_size, void* d_ws, size_t ws_size,
                              hipStream_t stream) {
    (void)in_sizes; (void)n_in; (void)out_size; (void)ws_size;
    const float* x      = (const float*)d_in[0];
    const int*   ei     = (const int*)d_in[1];
    const float* ea     = (const float*)d_in[2];
    const int*   batch  = (const int*)d_in[3];
    const float* emb_w  = (const float*)d_in[4];
    const float* emb_b  = (const float*)d_in[5];
    const float* msg_w  = (const float*)d_in[6];
    const float* msg_b  = (const float*)d_in[7];
    const float* gate_w = (const float*)d_in[8];
    const float* gate_b = (const float*)d_in[9];
    const float* ro1w   = (const float*)d_in[10];
    const float* ro1b   = (const float*)d_in[11];
    const float* ro2w   = (const float*)d_in[12];
    const float* ro2b   = (const float*)d_in[13];
    float* out = (float*)d_out;

    char* wsb = (char*)d_ws;
    float* h     = (float*)wsb;                 wsb += (size_t)NNODES * HID * 4;     // 25.6 MB
    float* aggr  = (float*)wsb;                 wsb += (size_t)NNODES * HID * 4;     // 25.6 MB
    float* nprec = (float*)wsb;                 wsb += (size_t)NNODES * 256 * 4;     // 51.2 MB
    half8* wfrag = (half8*)wsb;                 wsb += (size_t)NCONV * 16 * KSTEPS * 64 * 16;
    int* cnt     = (int*)wsb;                   wsb += (size_t)NNODES * 4;
    int* cursor  = (int*)wsb;                   wsb += (size_t)NNODES * 4;
    int* perm    = (int*)wsb;                   wsb += (size_t)NEDGES * 4;
    int* dstS    = (int*)wsb;                   wsb += (size_t)NEDGES * 4;
    int* srcS    = (int*)wsb;                   wsb += (size_t)NEDGES * 4;

    // ---- counting sort of edges by dst (reused across layers) ----
    hipMemsetAsync(cnt, 0, (size_t)NNODES * 4, stream);
    hist_kernel<<<NEDGES / 256, 256, 0, stream>>>(ei, cnt);
    scan_kernel<<<1, SCAN_T, 0, stream>>>(cnt, cursor);
    scatter_kernel<<<NEDGES / 256, 256, 0, stream>>>(ei, cursor, perm, dstS, srcS);

    const int wtotal = NCONV * 16 * KSTEPS * 64;
    prep_wfrag<<<(wtotal + 255) / 256, 256, 0, stream>>>(msg_w, gate_w, wfrag);
    embed_kernel<<<NNODES, HID, 0, stream>>>(x, emb_w, emb_b, h);

    for (int l = 0; l < NCONV; ++l) {
        hipMemsetAsync(aggr, 0, (size_t)NNODES * HID * 4, stream);
        node_pre_kernel<<<(NNODES + 31) / 32, 256, 0, stream>>>(
            h, wfrag + (size_t)l * 16 * KSTEPS * 64,
            msg_b + l * HID, gate_b + l * HID, nprec);
        edge_mfma_kernel<<<NEDGES / ME, 256, 0, stream>>>(
            h, dstS, srcS, perm, ea, wfrag + (size_t)l * 16 * KSTEPS * 64,
            nprec, aggr);
        update_kernel<<<(NNODES * HID / 4) / 256, 256, 0, stream>>>(h, aggr);
    }

    readout_kernel<<<NGRAPHS, HID, 0, stream>>>(h, batch, ro1w, ro1b, ro2w, ro2b, out);
}